// Round 10
// baseline (73.510 us; speedup 1.0000x reference)
//
#include <hip/hip_runtime.h>
#include <math.h>

#define H       2048
#define E       64
#define TOKENS  16384
#define BATCH   4
#define NBLK    512

typedef _Float16 f16x8  __attribute__((ext_vector_type(8)));
typedef float    f32x16 __attribute__((ext_vector_type(16)));

// ws float offsets
#define WHI_OFF  0          // 131072 f16 = 65536 floats
#define WLO_OFF  65536      // 131072 f16
#define PART_OFF 131072     // NBLK * 128 floats (psum[64] | cnt[64])
#define TICK_OFF 196608     // 1 uint ticket

// ---- W fp32 -> tiled f16 hi/lo in 32x32x16 B-fragment order (proven) ----
// slot s = (kg*2 + et)*64 + l ; e = et*32 + (l&31) ; k = kg*16 + (l>>5)*8 + j
__global__ __launch_bounds__(256)
void wconv(const float* __restrict__ W, _Float16* __restrict__ whi,
           _Float16* __restrict__ wlo, unsigned* __restrict__ ticket)
{
    const int s  = blockIdx.x * 256 + threadIdx.x;   // 0..16383
    const int kg = s >> 7;
    const int et = (s >> 6) & 1;
    const int l  = s & 63;
    const int e  = et * 32 + (l & 31);
    const int kb = kg * 16 + ((l >> 5) << 3);
    const float4 a = *(const float4*)(W + (size_t)e * H + kb);
    const float4 b = *(const float4*)(W + (size_t)e * H + kb + 4);
    const float xv[8] = {a.x, a.y, a.z, a.w, b.x, b.y, b.z, b.w};
    f16x8 hi, lo;
    #pragma unroll
    for (int j = 0; j < 8; ++j) {
        const _Float16 h = (_Float16)xv[j];
        hi[j] = h;
        lo[j] = (_Float16)(xv[j] - (float)h);
    }
    *(f16x8*)(whi + (size_t)s * 8) = hi;
    *(f16x8*)(wlo + (size_t)s * 8) = lo;
    if (s == 0) *ticket = 0u;    // reset ticket (kernel-boundary makes it visible)
}

// ---- main: 512 blocks x 512 thr (2 blocks/CU, 4 waves/SIMD) + ticket aux tail ----
// wave = ks 0..7 (K-slice of 256); each wave: 32 tokens x 64 experts via 2x mfma_32x32x16
__global__ __launch_bounds__(512, 4)
void router_main(const float* __restrict__ x,
                 const _Float16* __restrict__ whi,
                 const _Float16* __restrict__ wlo,
                 float* __restrict__ out,
                 float* __restrict__ part,
                 unsigned* __restrict__ ticket)
{
    __shared__ float lds[16384];   // 64 KB: partials, then epilogue scratch
    __shared__ unsigned lastf;

    const int tid = threadIdx.x;
    const int l   = tid & 63;
    const int ks  = tid >> 6;      // 0..7

    const int    trow = blockIdx.x * 32 + (l & 31);          // A row = lane&31
    const float* xb   = x + (size_t)trow * H + ks * 256 + ((l >> 5) << 3);
    const f16x8* bhp  = (const f16x8*)whi + (size_t)(ks * 16) * 128 + l;  // 128 slots/kg
    const f16x8* blp  = (const f16x8*)wlo + (size_t)(ks * 16) * 128 + l;

    f32x16 acc[2];
    #pragma unroll
    for (int et = 0; et < 2; ++et)
        #pragma unroll
        for (int i = 0; i < 16; ++i) acc[et][i] = 0.f;

    // 2-deep A prefetch, 1-deep B prefetch
    float4 a0c = *(const float4*)xb,        a1c = *(const float4*)(xb + 4);
    float4 a0n = *(const float4*)(xb + 16), a1n = *(const float4*)(xb + 20);
    f16x8 b0h = bhp[0], b1h = bhp[64], b0l = blp[0], b1l = blp[64];

    #pragma unroll
    for (int kk = 0; kk < 16; ++kk) {
        float4 a0nn = a0n, a1nn = a1n;
        if (kk < 14) {
            a0nn = *(const float4*)(xb + (kk + 2) * 16);
            a1nn = *(const float4*)(xb + (kk + 2) * 16 + 4);
        }
        f16x8 nb0h = b0h, nb1h = b1h, nb0l = b0l, nb1l = b1l;
        if (kk < 15) {
            nb0h = bhp[(kk + 1) * 128];      nb1h = bhp[(kk + 1) * 128 + 64];
            nb0l = blp[(kk + 1) * 128];      nb1l = blp[(kk + 1) * 128 + 64];
        }
        const float xv[8] = {a0c.x, a0c.y, a0c.z, a0c.w, a1c.x, a1c.y, a1c.z, a1c.w};
        f16x8 ahi, alo;
        #pragma unroll
        for (int j = 0; j < 8; ++j) {
            const _Float16 h = (_Float16)xv[j];
            ahi[j] = h;
            alo[j] = (_Float16)(xv[j] - (float)h);
        }
        acc[0] = __builtin_amdgcn_mfma_f32_32x32x16_f16(ahi, b0h, acc[0], 0, 0, 0);
        acc[0] = __builtin_amdgcn_mfma_f32_32x32x16_f16(ahi, b0l, acc[0], 0, 0, 0);
        acc[0] = __builtin_amdgcn_mfma_f32_32x32x16_f16(alo, b0h, acc[0], 0, 0, 0);
        acc[1] = __builtin_amdgcn_mfma_f32_32x32x16_f16(ahi, b1h, acc[1], 0, 0, 0);
        acc[1] = __builtin_amdgcn_mfma_f32_32x32x16_f16(ahi, b1l, acc[1], 0, 0, 0);
        acc[1] = __builtin_amdgcn_mfma_f32_32x32x16_f16(alo, b1h, acc[1], 0, 0, 0);
        a0c = a0n; a1c = a1n; a0n = a0nn; a1n = a1nn;
        b0h = nb0h; b1h = nb1h; b0l = nb0l; b1l = nb1l;
    }

    // ---- write K-slice partials: row=(r&3)+8*(r>>2)+4*(l>>5), col=et*32+(l&31)
    #pragma unroll
    for (int et = 0; et < 2; ++et)
        #pragma unroll
        for (int r = 0; r < 16; ++r) {
            const int row = (r & 3) + 8 * (r >> 2) + 4 * (l >> 5);
            lds[(ks * 32 + row) * 64 + et * 32 + (l & 31)] = acc[et][r];
        }
    __syncthreads();

    // ---- reduce over 8 ks (512 thr: t=tid>>4, c4=(tid&15)*4), write [32][65]
    {
        const int t = tid >> 4, c4 = (tid & 15) * 4;
        float s0 = 0.f, s1 = 0.f, s2 = 0.f, s3 = 0.f;
        #pragma unroll
        for (int k2 = 0; k2 < 8; ++k2) {
            const float4 v = *(const float4*)&lds[(k2 * 32 + t) * 64 + c4];
            s0 += v.x; s1 += v.y; s2 += v.z; s3 += v.w;
        }
        __syncthreads();    // all partial reads done before overwrite
        lds[t * 65 + c4 + 0] = s0;
        lds[t * 65 + c4 + 1] = s1;
        lds[t * 65 + c4 + 2] = s2;
        lds[t * 65 + c4 + 3] = s3;
    }
    __syncthreads();

    // ---- wave-0 epilogue: lanes 0..31 = tokens (proven serial structure)
    const int w = tid >> 6;
    #define SC_OFF   2112
    #define HIST_OFF 6272
    int i1 = 0, i2 = 0;
    if (w == 0 && l < 32) {
        float lg[64];
        #pragma unroll
        for (int e = 0; e < 64; ++e) lg[e] = lds[l * 65 + e];
        float v1 = lg[0];
        #pragma unroll
        for (int e = 1; e < 64; ++e) { if (lg[e] > v1) { v1 = lg[e]; i1 = e; } }
        float v2 = -INFINITY;
        #pragma unroll
        for (int e = 0; e < 64; ++e) { if (e != i1 && lg[e] > v2) { v2 = lg[e]; i2 = e; } }
        float den = 0.f;
        #pragma unroll
        for (int e = 0; e < 64; ++e) den += __expf(lg[e] - v1);
        const float inv_den = 1.f / den;
        const float s1 = inv_den;                    // exp(v1-v1)/den
        const float s2 = __expf(v2 - v1) * inv_den;
        const float rs = 1.f / (s1 + s2 + 1e-20f);
        const int gt = blockIdx.x * 32 + l;
        *(float2*)&out[2 * gt]              = make_float2((float)i1, (float)i2);
        *(float2*)&out[2 * TOKENS + 2 * gt] = make_float2(s1 * rs, s2 * rs);
        // scores, rotated columns for conflict-free column sums
        #pragma unroll
        for (int e = 0; e < 64; ++e)
            lds[SC_OFF + l * 64 + ((e + l) & 63)] = __expf(lg[e] - v1) * inv_den;
    }
    __syncthreads();
    if (w == 0) {
        float cs = 0.f;                  // expert l's score sum over 32 tokens
        #pragma unroll
        for (int r = 0; r < 32; ++r) cs += lds[SC_OFF + r * 64 + ((l + r) & 63)];
        part[blockIdx.x * 128 + l] = cs;
        lds[HIST_OFF + l] = 0.f;
    }
    __syncthreads();
    if (w == 0 && l < 32) {
        atomicAdd(&lds[HIST_OFF + i1], 1.f);
        atomicAdd(&lds[HIST_OFF + i2], 1.f);
    }
    __syncthreads();
    if (w == 0) part[blockIdx.x * 128 + 64 + l] = lds[HIST_OFF + l];

    // ======== fused aux tail: last block reduces all partials (pipelined sc1 loads) ========
    __syncthreads();                 // all part[] stores drained to L2
    if (tid == 0) {
        __threadfence();             // release: write back this XCD's L2
        const unsigned old = __hip_atomic_fetch_add(ticket, 1u, __ATOMIC_ACQ_REL,
                                                    __HIP_MEMORY_SCOPE_AGENT);
        lastf = (old == NBLK - 1u) ? 1u : 0u;
    }
    __syncthreads();
    if (lastf) {                     // block-uniform branch
        const int half = tid >> 8;   // 0..1 splits j-range
        const int be   = tid & 255;
        const int b = be >> 6, e = be & 63;
        float ps = 0.f, ct = 0.f;
        #pragma unroll 4
        for (int j = half * 64; j < half * 64 + 64; ++j) {   // 128 blocks per batch
            const int base = (b * 128 + j) * 128;
            // relaxed agent-scope loads: coherent (bypass stale L1/L2), still pipelined
            ps += __hip_atomic_load(&part[base + e],      __ATOMIC_RELAXED,
                                    __HIP_MEMORY_SCOPE_AGENT);
            ct += __hip_atomic_load(&part[base + 64 + e], __ATOMIC_RELAXED,
                                    __HIP_MEMORY_SCOPE_AGENT);
        }
        lds[tid]       = ps;
        lds[512 + tid] = ct;
        __syncthreads();
        if (tid < 256) {
            const float psf = lds[tid] + lds[tid + 256];
            const float ctf = lds[512 + tid] + lds[512 + tid + 256];
            // ce = ctf * E/(S*k); meanprob = psf/S
            float val = ctf * (64.0f / (4096.0f * 2.0f)) * (psf / 4096.0f);
            #pragma unroll
            for (int off = 32; off > 0; off >>= 1) val += __shfl_xor(val, off, 64);
            if ((tid & 63) == 0) lds[1024 + (tid >> 6)] = val;
        }
        __syncthreads();
        if (tid == 0)
            out[4 * TOKENS] = (lds[1024] + lds[1025] + lds[1026] + lds[1027]) * (0.001f / 4.0f);
    }
}

extern "C" void kernel_launch(void* const* d_in, const int* in_sizes, int n_in,
                              void* d_out, int out_size, void* d_ws, size_t ws_size,
                              hipStream_t stream)
{
    (void)in_sizes; (void)n_in; (void)out_size; (void)ws_size;
    const float* x = (const float*)d_in[0];
    const float* W = (const float*)d_in[1];
    float* out = (float*)d_out;
    float* ws  = (float*)d_ws;

    _Float16* whi    = (_Float16*)(ws + WHI_OFF);
    _Float16* wlo    = (_Float16*)(ws + WLO_OFF);
    float*    part   = ws + PART_OFF;
    unsigned* ticket = (unsigned*)(ws + TICK_OFF);

    hipLaunchKernelGGL(wconv, dim3(64), dim3(256), 0, stream, W, whi, wlo, ticket);
    hipLaunchKernelGGL(router_main, dim3(NBLK), dim3(512), 0, stream,
                       x, whi, wlo, out, part, ticket);
}

// Round 11
// 49.185 us; speedup vs baseline: 1.4946x; 1.4946x over previous
//
#include <hip/hip_runtime.h>
#include <math.h>

#define H       2048
#define E       64
#define TOKENS  16384
#define BATCH   4
#define NBLK    256

typedef _Float16 f16x8  __attribute__((ext_vector_type(8)));
typedef float    f32x16 __attribute__((ext_vector_type(16)));

// ws float offsets
#define WHI_OFF  0          // 131072 f16 = 65536 floats
#define WLO_OFF  65536      // 131072 f16
#define PART_OFF 131072     // NBLK * 128 floats (psum[64] | cnt[64])

// LDS float offsets (64 KB arena; partials region reused after reduce)
#define SC_OFF   4224
#define HIST_OFF 8320

// ---- W fp32 -> tiled f16 hi/lo in 32x32x16 B-fragment order (proven) ----
// slot s = (kg*2 + et)*64 + l ; e = et*32 + (l&31) ; k = kg*16 + (l>>5)*8 + j
__global__ __launch_bounds__(256)
void wconv(const float* __restrict__ W, _Float16* __restrict__ whi,
           _Float16* __restrict__ wlo)
{
    const int s  = blockIdx.x * 256 + threadIdx.x;   // 0..16383
    const int kg = s >> 7;
    const int et = (s >> 6) & 1;
    const int l  = s & 63;
    const int e  = et * 32 + (l & 31);
    const int kb = kg * 16 + ((l >> 5) << 3);
    const float4 a = *(const float4*)(W + (size_t)e * H + kb);
    const float4 b = *(const float4*)(W + (size_t)e * H + kb + 4);
    const float xv[8] = {a.x, a.y, a.z, a.w, b.x, b.y, b.z, b.w};
    f16x8 hi, lo;
    #pragma unroll
    for (int j = 0; j < 8; ++j) {
        const _Float16 h = (_Float16)xv[j];
        hi[j] = h;
        lo[j] = (_Float16)(xv[j] - (float)h);
    }
    *(f16x8*)(whi + (size_t)s * 8) = hi;
    *(f16x8*)(wlo + (size_t)s * 8) = lo;
}

// ---- main: 256 blocks x 512 thr (1 block/CU); wave = ks 0..7 (K=256) ----
// Each wave: 64 tokens (2 A-tiles) x 64 experts sharing one B-register set.
__global__ __launch_bounds__(512, 2)
void router_main(const float* __restrict__ x,
                 const _Float16* __restrict__ whi,
                 const _Float16* __restrict__ wlo,
                 float* __restrict__ out,
                 float* __restrict__ part)
{
    __shared__ float lds[16384];   // 64 KB

    const int tid = threadIdx.x;
    const int l   = tid & 63;
    const int ks  = tid >> 6;      // 0..7
    const int t0  = blockIdx.x * 64;

    const int la  = l & 31;
    const int hi5 = l >> 5;

    const float* xb0 = x + (size_t)(t0 + la) * H + ks * 256 + (hi5 << 3);
    const float* xb1 = xb0 + (size_t)32 * H;
    const f16x8* bhp = (const f16x8*)whi + (size_t)(ks * 16) * 128 + l;
    const f16x8* blp = (const f16x8*)wlo + (size_t)(ks * 16) * 128 + l;

    f32x16 acc00, acc01, acc10, acc11;   // [tile][et]
    #pragma unroll
    for (int i = 0; i < 16; ++i) { acc00[i] = 0.f; acc01[i] = 0.f; acc10[i] = 0.f; acc11[i] = 0.f; }

    // A: 3-gen rotation (2-deep prefetch); B: 2-gen (1-deep)
    float4 Ar[3][4];     // [gen][tile0-lo, tile0-hi, tile1-lo, tile1-hi]
    f16x8  Br[2][4];     // [gen][h_et0, h_et1, lo_et0, lo_et1]

    #pragma unroll
    for (int g = 0; g < 2; ++g) {
        Ar[g][0] = *(const float4*)(xb0 + g * 16);
        Ar[g][1] = *(const float4*)(xb0 + g * 16 + 4);
        Ar[g][2] = *(const float4*)(xb1 + g * 16);
        Ar[g][3] = *(const float4*)(xb1 + g * 16 + 4);
    }
    Br[0][0] = bhp[0]; Br[0][1] = bhp[64]; Br[0][2] = blp[0]; Br[0][3] = blp[64];

    #pragma unroll
    for (int kk = 0; kk < 16; ++kk) {
        const int cg = kk % 3, ng = (kk + 2) % 3;
        const int cb = kk & 1, nb = (kk + 1) & 1;
        if (kk < 14) {
            Ar[ng][0] = *(const float4*)(xb0 + (kk + 2) * 16);
            Ar[ng][1] = *(const float4*)(xb0 + (kk + 2) * 16 + 4);
            Ar[ng][2] = *(const float4*)(xb1 + (kk + 2) * 16);
            Ar[ng][3] = *(const float4*)(xb1 + (kk + 2) * 16 + 4);
        }
        if (kk < 15) {
            Br[nb][0] = bhp[(kk + 1) * 128];      Br[nb][1] = bhp[(kk + 1) * 128 + 64];
            Br[nb][2] = blp[(kk + 1) * 128];      Br[nb][3] = blp[(kk + 1) * 128 + 64];
        }
        const float xv0[8] = {Ar[cg][0].x, Ar[cg][0].y, Ar[cg][0].z, Ar[cg][0].w,
                              Ar[cg][1].x, Ar[cg][1].y, Ar[cg][1].z, Ar[cg][1].w};
        const float xv1[8] = {Ar[cg][2].x, Ar[cg][2].y, Ar[cg][2].z, Ar[cg][2].w,
                              Ar[cg][3].x, Ar[cg][3].y, Ar[cg][3].z, Ar[cg][3].w};
        f16x8 ah0, al0, ah1, al1;
        #pragma unroll
        for (int j = 0; j < 8; ++j) {
            const _Float16 h0 = (_Float16)xv0[j];
            ah0[j] = h0; al0[j] = (_Float16)(xv0[j] - (float)h0);
            const _Float16 h1 = (_Float16)xv1[j];
            ah1[j] = h1; al1[j] = (_Float16)(xv1[j] - (float)h1);
        }
        acc00 = __builtin_amdgcn_mfma_f32_32x32x16_f16(ah0, Br[cb][0], acc00, 0, 0, 0);
        acc00 = __builtin_amdgcn_mfma_f32_32x32x16_f16(ah0, Br[cb][2], acc00, 0, 0, 0);
        acc00 = __builtin_amdgcn_mfma_f32_32x32x16_f16(al0, Br[cb][0], acc00, 0, 0, 0);
        acc01 = __builtin_amdgcn_mfma_f32_32x32x16_f16(ah0, Br[cb][1], acc01, 0, 0, 0);
        acc01 = __builtin_amdgcn_mfma_f32_32x32x16_f16(ah0, Br[cb][3], acc01, 0, 0, 0);
        acc01 = __builtin_amdgcn_mfma_f32_32x32x16_f16(al0, Br[cb][1], acc01, 0, 0, 0);
        acc10 = __builtin_amdgcn_mfma_f32_32x32x16_f16(ah1, Br[cb][0], acc10, 0, 0, 0);
        acc10 = __builtin_amdgcn_mfma_f32_32x32x16_f16(ah1, Br[cb][2], acc10, 0, 0, 0);
        acc10 = __builtin_amdgcn_mfma_f32_32x32x16_f16(al1, Br[cb][0], acc10, 0, 0, 0);
        acc11 = __builtin_amdgcn_mfma_f32_32x32x16_f16(ah1, Br[cb][1], acc11, 0, 0, 0);
        acc11 = __builtin_amdgcn_mfma_f32_32x32x16_f16(ah1, Br[cb][3], acc11, 0, 0, 0);
        acc11 = __builtin_amdgcn_mfma_f32_32x32x16_f16(al1, Br[cb][1], acc11, 0, 0, 0);
    }

    // ---- partials [4][64 t][64 e]: ks<4 store, then ks>=4 += (exact 2-addend sums)
    const int ksl = ks & 3;
    // C/D: row=(r&3)+8*(r>>2)+4*hi5, token = tile*32+row, col = et*32+la
    if (ks < 4) {
        #pragma unroll
        for (int r = 0; r < 16; ++r) {
            const int row = (r & 3) + 8 * (r >> 2) + 4 * hi5;
            lds[ksl * 4096 + row * 64 + la]             = acc00[r];
            lds[ksl * 4096 + row * 64 + 32 + la]        = acc01[r];
            lds[ksl * 4096 + (32 + row) * 64 + la]      = acc10[r];
            lds[ksl * 4096 + (32 + row) * 64 + 32 + la] = acc11[r];
        }
    }
    __syncthreads();
    if (ks >= 4) {
        #pragma unroll
        for (int r = 0; r < 16; ++r) {
            const int row = (r & 3) + 8 * (r >> 2) + 4 * hi5;
            lds[ksl * 4096 + row * 64 + la]             += acc00[r];
            lds[ksl * 4096 + row * 64 + 32 + la]        += acc01[r];
            lds[ksl * 4096 + (32 + row) * 64 + la]      += acc10[r];
            lds[ksl * 4096 + (32 + row) * 64 + 32 + la] += acc11[r];
        }
    }
    __syncthreads();

    // ---- reduce over 4 slots -> fin [64][65] (r5-proven 16-lane x float4 mapping)
    {
        float4 s[2];
        #pragma unroll
        for (int rep = 0; rep < 2; ++rep) {
            const int t  = rep * 32 + (tid >> 4);
            const int c4 = (tid & 15) * 4;
            float4 a4 = make_float4(0.f, 0.f, 0.f, 0.f);
            #pragma unroll
            for (int k4 = 0; k4 < 4; ++k4) {
                const float4 v = *(const float4*)&lds[k4 * 4096 + t * 64 + c4];
                a4.x += v.x; a4.y += v.y; a4.z += v.z; a4.w += v.w;
            }
            s[rep] = a4;
        }
        __syncthreads();    // all partial reads done before overwrite
        #pragma unroll
        for (int rep = 0; rep < 2; ++rep) {
            const int t  = rep * 32 + (tid >> 4);
            const int c4 = (tid & 15) * 4;
            lds[t * 65 + c4 + 0] = s[rep].x;
            lds[t * 65 + c4 + 1] = s[rep].y;
            lds[t * 65 + c4 + 2] = s[rep].z;
            lds[t * 65 + c4 + 3] = s[rep].w;
        }
    }
    __syncthreads();

    // ---- wave-0 epilogue: 64 lanes = 64 tokens (proven serial structure)
    const int w = tid >> 6;
    int i1 = 0, i2 = 0;
    if (w == 0) {
        float lg[64];
        #pragma unroll
        for (int e = 0; e < 64; ++e) lg[e] = lds[l * 65 + e];
        float v1 = lg[0];
        #pragma unroll
        for (int e = 1; e < 64; ++e) { if (lg[e] > v1) { v1 = lg[e]; i1 = e; } }
        float v2 = -INFINITY;
        #pragma unroll
        for (int e = 0; e < 64; ++e) { if (e != i1 && lg[e] > v2) { v2 = lg[e]; i2 = e; } }
        float den = 0.f;
        #pragma unroll
        for (int e = 0; e < 64; ++e) den += __expf(lg[e] - v1);
        const float inv_den = 1.f / den;
        const float s1 = inv_den;                    // exp(v1-v1)/den
        const float s2 = __expf(v2 - v1) * inv_den;
        const float rs = 1.f / (s1 + s2 + 1e-20f);
        const int gt = t0 + l;
        *(float2*)&out[2 * gt]              = make_float2((float)i1, (float)i2);
        *(float2*)&out[2 * TOKENS + 2 * gt] = make_float2(s1 * rs, s2 * rs);
        // scores, rotated columns for conflict-free column sums
        #pragma unroll
        for (int e = 0; e < 64; ++e)
            lds[SC_OFF + l * 64 + ((e + l) & 63)] = __expf(lg[e] - v1) * inv_den;
        lds[HIST_OFF + l] = 0.f;
    }
    __syncthreads();
    if (w == 0) {
        atomicAdd(&lds[HIST_OFF + i1], 1.f);
        atomicAdd(&lds[HIST_OFF + i2], 1.f);
    }
    __syncthreads();
    if (w == 0) {
        float cs = 0.f;                  // expert l's score sum over 64 tokens
        #pragma unroll
        for (int r = 0; r < 64; ++r) cs += lds[SC_OFF + r * 64 + ((l + r) & 63)];
        part[blockIdx.x * 128 + l]      = cs;
        part[blockIdx.x * 128 + 64 + l] = lds[HIST_OFF + l];
    }
}

// ---- aux loss finalize: reduce 256 per-block partials ----
__global__ __launch_bounds__(256)
void router_aux(const float* __restrict__ part, float* __restrict__ out)
{
    const int tid = threadIdx.x;    // 256 = BATCH*E
    const int b = tid >> 6, e = tid & 63;
    float ps = 0.f, ct = 0.f;
    for (int j = 0; j < 64; ++j) {           // 64 blocks per batch
        const int base = (b * 64 + j) * 128;
        ps += part[base + e];                // coalesced: lanes -> consecutive e
        ct += part[base + 64 + e];
    }
    // ce = ct * E/(S*k); meanprob = ps/S
    float val = ct * (64.0f / (4096.0f * 2.0f)) * (ps / 4096.0f);
    #pragma unroll
    for (int off = 32; off > 0; off >>= 1) val += __shfl_xor(val, off, 64);
    __shared__ float red[4];
    if ((tid & 63) == 0) red[tid >> 6] = val;
    __syncthreads();
    if (tid == 0)
        out[4 * TOKENS] = (red[0] + red[1] + red[2] + red[3]) * (0.001f / 4.0f);
}

extern "C" void kernel_launch(void* const* d_in, const int* in_sizes, int n_in,
                              void* d_out, int out_size, void* d_ws, size_t ws_size,
                              hipStream_t stream)
{
    (void)in_sizes; (void)n_in; (void)out_size; (void)ws_size;
    const float* x = (const float*)d_in[0];
    const float* W = (const float*)d_in[1];
    float* out = (float*)d_out;
    float* ws  = (float*)d_ws;

    _Float16* whi  = (_Float16*)(ws + WHI_OFF);
    _Float16* wlo  = (_Float16*)(ws + WLO_OFF);
    float*    part = ws + PART_OFF;

    hipLaunchKernelGGL(wconv, dim3(64), dim3(256), 0, stream, W, whi, wlo);
    hipLaunchKernelGGL(router_main, dim3(NBLK), dim3(512), 0, stream,
                       x, whi, wlo, out, part);
    hipLaunchKernelGGL(router_aux, dim3(1), dim3(256), 0, stream, part, out);
}